// Round 5
// baseline (124.804 us; speedup 1.0000x reference)
//
#include <hip/hip_runtime.h>

typedef __bf16 bf16_t;
typedef __bf16 bf16x8 __attribute__((ext_vector_type(8)));
typedef float  f32x4  __attribute__((ext_vector_type(4)));

#define HPAD   132          // f32 h-tile row stride (528B, 16B multiple)
#define LDSPAD 136          // bf16 tile stride: 272B (16B multiple)
#define VPAD   40           // 32 + 8 pad -> 80B stride

__device__ __forceinline__ bf16x8 cvt44(float4 a, float4 b) {
    bf16x8 v;
    v[0] = (bf16_t)a.x; v[1] = (bf16_t)a.y; v[2] = (bf16_t)a.z; v[3] = (bf16_t)a.w;
    v[4] = (bf16_t)b.x; v[5] = (bf16_t)b.y; v[6] = (bf16_t)b.z; v[7] = (bf16_t)b.w;
    return v;
}

__global__ __launch_bounds__(1024)
void nextdist_fused(const float* __restrict__ h,      // [2048][128]
                    const float* __restrict__ pos,    // [2048][3]
                    const float* __restrict__ ntype,  // [64][64]
                    const float* __restrict__ Wemb,   // [128][64]
                    const float* __restrict__ Wqkv,   // [384][128]
                    const float* __restrict__ bqkv,   // [384]
                    const float* __restrict__ Wg,     // [128]
                    const float* __restrict__ bg,     // [1]
                    const float* __restrict__ Wt,     // [32]
                    const float* __restrict__ bt,     // [1]
                    const float* __restrict__ Wd0, const float* __restrict__ bd0, // [106][128],[106]
                    const float* __restrict__ Wd1, const float* __restrict__ bd1, // [85][106],[85]
                    const float* __restrict__ Wd2, const float* __restrict__ bd2, // [64][85],[64]
                    float* __restrict__ out)          // [2048][64]
{
    __shared__ __align__(16) float  s_hf[32 * HPAD];     // h tile, f32 (residual + x source)
    __shared__ __align__(16) bf16_t s_x [32 * LDSPAD];   // x (bf16), later vals
    __shared__ __align__(16) bf16_t s_q [32 * LDSPAD];   // q, later y0 (zero-padded cols 106..127)
    __shared__ __align__(16) bf16_t s_k [32 * LDSPAD];   // k, later y1 (zero-padded cols 85..95)
    __shared__ __align__(16) bf16_t s_vT[128 * VPAD];    // v transposed: [feat][atom]
    __shared__ __align__(16) bf16_t s_p [32 * VPAD];     // softmax probs (bf16)
    __shared__ __align__(16) float  s_t [32 * 33];       // t matrix, then logits
    __shared__ __align__(16) float  s_y2[32 * 66];       // final pre-softmax logits (f32)
    __shared__ float s_emb[128];
    __shared__ float s_nt[64];
    __shared__ float s_pos[96];
    __shared__ float s_wt[32];
    __shared__ float s_wg[128];
    __shared__ float s_gate[32];

    const int tid  = threadIdx.x;
    const int wave = tid >> 6;           // 0..15
    const int lane = tid & 63;
    const int quad = lane >> 4;
    const int l16  = lane & 15;
    const int g    = blockIdx.x;
    const int base = g * 32;

    // ---------- Phase 1: stage inputs (1024 threads, 1 float4 each) ----------
    {
        int a = tid >> 5, ch = tid & 31;
        *(float4*)&s_hf[a * HPAD + ch * 4] = *(const float4*)&h[(base + a) * 128 + ch * 4];
    }
    if (tid < 96)  s_pos[tid] = pos[base * 3 + tid];
    if (tid < 64)  s_nt[tid]  = ntype[g * 64 + tid];
    if (tid < 32)  s_wt[tid]  = Wt[tid];
    if (tid < 128) s_wg[tid]  = Wg[tid];

    // ---- Early prefetch: Wemb fragments (f32) + phase-3 Wqkv (f32 -> bf16 in regs) ----
    float4 we0, we1;
    {
        int o = tid >> 3, p = tid & 7;
        we0 = *(const float4*)&Wemb[o * 64 + p * 8];
        we1 = *(const float4*)&Wemb[o * 64 + p * 8 + 4];
    }
    const float bt0 = bt[0];
    const float bg0 = bg[0];
    bf16x8 wq[3][4]; float bq3[3];
#pragma unroll
    for (int t3 = 0; t3 < 3; ++t3) {
        int t = wave + t3 * 16;
        int o = (t >> 1) * 16 + l16;                      // 0..383, each exactly once
        const float* wrow = &Wqkv[o * 128];
#pragma unroll
        for (int ks = 0; ks < 4; ++ks) {
            float4 a = *(const float4*)&wrow[ks * 32 + quad * 8];
            float4 b = *(const float4*)&wrow[ks * 32 + quad * 8 + 4];
            wq[t3][ks] = cvt44(a, b);
        }
        bq3[t3] = bqkv[o];
    }
    __syncthreads();

    // ---------- Phase 1b: emb = W_emb @ next_type[g]  (8 threads / output) ----------
    {
        int o = tid >> 3, p = tid & 7;
        const float* nt8 = &s_nt[p * 8];
        float acc = we0.x * nt8[0] + we0.y * nt8[1] + we0.z * nt8[2] + we0.w * nt8[3]
                  + we1.x * nt8[4] + we1.y * nt8[5] + we1.z * nt8[6] + we1.w * nt8[7];
#pragma unroll
        for (int s = 1; s < 8; s <<= 1) acc += __shfl_xor(acc, s, 64);
        if (p == 0) s_emb[o] = acc;
    }

    // ---------- Phase 4 (moved early): t[i][j] = sum_k Wt[k]*exp(-10*(d_ij-c_k)^2) + bt ----------
    {
        int i = tid >> 5, j = tid & 31;
        float dx = s_pos[i * 3 + 0] - s_pos[j * 3 + 0];
        float dy = s_pos[i * 3 + 1] - s_pos[j * 3 + 1];
        float dz = s_pos[i * 3 + 2] - s_pos[j * 3 + 2];
        float d  = sqrtf(fmaxf(dx * dx + dy * dy + dz * dz, 1e-12f));
        float acc = bt0;
#pragma unroll
        for (int kk = 0; kk < 32; ++kk) {
            float u = d - (float)kk * (10.0f / 31.0f);
            acc += s_wt[kk] * __expf(-10.0f * u * u);
        }
        s_t[i * 33 + j] = acc;
    }
    __syncthreads();

    // ---------- Phase 2: x = h * emb (bf16 for MFMA); gate = sigmoid(x.Wg + bg) ----------
    for (int c = tid; c < 4096; c += 1024) {
        int a = c >> 7, f = c & 127;
        s_x[a * LDSPAD + f] = (bf16_t)(s_hf[a * HPAD + f] * s_emb[f]);
    }
    if (tid < 256) {
        int r = tid >> 3, p = tid & 7;
        float acc = 0.0f;
#pragma unroll
        for (int f = p * 16; f < p * 16 + 16; ++f) acc += s_hf[r * HPAD + f] * s_emb[f] * s_wg[f];
#pragma unroll
        for (int s = 1; s < 8; s <<= 1) acc += __shfl_xor(acc, s, 64);
        if (p == 0) s_gate[r] = 1.0f / (1.0f + __expf(-(acc + bg0)));
    }
    __syncthreads();

    // ---------- Phase 3: qkv = x @ Wqkv^T + bqkv  (48 tile-tasks; weights prefetched) ----------
    {
        // mt = (wave + 16*t3) & 1 = wave & 1  -> A-fragments shared across the 3 tasks
        int mt = wave & 1;
        bf16x8 av[4];
#pragma unroll
        for (int ks = 0; ks < 4; ++ks)
            av[ks] = *(const bf16x8*)&s_x[(mt * 16 + l16) * LDSPAD + ks * 32 + quad * 8];
#pragma unroll
        for (int t3 = 0; t3 < 3; ++t3) {
            int t = wave + t3 * 16;
            int o = (t >> 1) * 16 + l16;
            f32x4 acc = {0.f, 0.f, 0.f, 0.f};
#pragma unroll
            for (int ks = 0; ks < 4; ++ks)
                acc = __builtin_amdgcn_mfma_f32_16x16x32_bf16(av[ks], wq[t3][ks], acc, 0, 0, 0);
            float bias = bq3[t3];
#pragma unroll
            for (int r = 0; r < 4; ++r) {
                int a = mt * 16 + quad * 4 + r;
                float val = acc[r] + bias;
                if (o < 128)      s_q[a * LDSPAD + o]         = (bf16_t)val;
                else if (o < 256) s_k[a * LDSPAD + (o - 128)] = (bf16_t)val;
                else              s_vT[(o - 256) * VPAD + a]  = (bf16_t)val;
            }
        }
    }

    // ---- Prefetch phase-8 weights Wd0 (f32->bf16, row-guarded; held across phases 5-7) ----
    bf16x8 w8[4]; float b8v = 0.0f;
    const int oD = (wave >> 1) * 16 + l16;                 // row index used by phases 8/9/10
    if (wave < 14) {
        bool rv = oD < 106;
        const float* wrow = &Wd0[oD * 128];
        float4 zf4 = make_float4(0.f, 0.f, 0.f, 0.f);
#pragma unroll
        for (int ks = 0; ks < 4; ++ks) {
            float4 a = rv ? *(const float4*)&wrow[ks * 32 + quad * 8]     : zf4;
            float4 b = rv ? *(const float4*)&wrow[ks * 32 + quad * 8 + 4] : zf4;
            w8[ks] = cvt44(a, b);
        }
        b8v = rv ? bd0[oD] : 0.0f;
    }
    __syncthreads();

    // ---------- Phase 5: logits = (q@k^T)/sqrt(32) + t   (b_bias cancels in softmax) ----------
    if (wave < 4) {
        int mt = wave >> 1, nt = wave & 1;
        f32x4 acc = {0.f, 0.f, 0.f, 0.f};
#pragma unroll
        for (int ks = 0; ks < 4; ++ks) {
            bf16x8 av = *(const bf16x8*)&s_q[(mt * 16 + l16) * LDSPAD + ks * 32 + quad * 8];
            bf16x8 bv = *(const bf16x8*)&s_k[(nt * 16 + l16) * LDSPAD + ks * 32 + quad * 8];
            acc = __builtin_amdgcn_mfma_f32_16x16x32_bf16(av, bv, acc, 0, 0, 0);
        }
#pragma unroll
        for (int r = 0; r < 4; ++r) {
            int i = mt * 16 + quad * 4 + r, j = nt * 16 + l16;
            s_t[i * 33 + j] = acc[r] * 0.17677669529663687f + s_t[i * 33 + j];
        }
    }
    __syncthreads();

    // ---------- Phase 6: row softmax -> P (bf16) ----------
    if (tid < 256) {
        int r = tid >> 3, sub = tid & 7;                  // 8 threads/row, 4 cols each
        float v[4]; float mx = -1e30f;
#pragma unroll
        for (int c = 0; c < 4; ++c) { v[c] = s_t[r * 33 + sub * 4 + c]; mx = fmaxf(mx, v[c]); }
#pragma unroll
        for (int s = 1; s < 8; s <<= 1) mx = fmaxf(mx, __shfl_xor(mx, s, 64));
        float sum = 0.0f;
#pragma unroll
        for (int c = 0; c < 4; ++c) { v[c] = __expf(v[c] - mx); sum += v[c]; }
#pragma unroll
        for (int s = 1; s < 8; s <<= 1) sum += __shfl_xor(sum, s, 64);
        float inv = 1.0f / sum;
#pragma unroll
        for (int c = 0; c < 4; ++c) s_p[r * VPAD + sub * 4 + c] = (bf16_t)(v[c] * inv);
    }
    __syncthreads();

    // ---------- Phase 7: vals = (P @ V) * gate + x  (16 tile-tasks, 1/wave) ----------
    {
        int nt = wave >> 1, mt = wave & 1;                 // nt 0..7 feature tile
        bf16x8 av = *(const bf16x8*)&s_p[(mt * 16 + l16) * VPAD + quad * 8];
        bf16x8 bv = *(const bf16x8*)&s_vT[(nt * 16 + l16) * VPAD + quad * 8];
        f32x4 acc = {0.f, 0.f, 0.f, 0.f};
        acc = __builtin_amdgcn_mfma_f32_16x16x32_bf16(av, bv, acc, 0, 0, 0);
#pragma unroll
        for (int r = 0; r < 4; ++r) {
            int a = mt * 16 + quad * 4 + r, f = nt * 16 + l16;
            float val = acc[r] * s_gate[a] + s_hf[a * HPAD + f] * s_emb[f];
            s_x[a * LDSPAD + f] = (bf16_t)val;             // vals overwrite x
        }
    }
    if (tid < 512) {                                       // zero y0 cols 112..127 (K-pad for phase 9)
        int a = tid >> 4, c = 112 + (tid & 15);
        s_q[a * LDSPAD + c] = (bf16_t)0.0f;
    }

    // ---- Prefetch phase-9 weights Wd1 [85][106] (rows 8B-aligned; pair-guarded) ----
    bf16x8 w9[4]; float b9v = 0.0f;
    if (wave < 12) {
        bool rv = oD < 85;
        const float* wrow = &Wd1[oD * 106];
#pragma unroll
        for (int ks = 0; ks < 4; ++ks) {
            int kb = ks * 32 + quad * 8;
            float tf[8];
#pragma unroll
            for (int pj = 0; pj < 4; ++pj) {
                int k2 = kb + pj * 2;                      // even; pair (k2,k2+1) never straddles 106
                if (rv && k2 < 106) {
                    float2 t2 = *(const float2*)&wrow[k2];
                    tf[pj * 2] = t2.x; tf[pj * 2 + 1] = t2.y;
                } else {
                    tf[pj * 2] = 0.0f; tf[pj * 2 + 1] = 0.0f;
                }
            }
            bf16x8 v;
#pragma unroll
            for (int jj = 0; jj < 8; ++jj) v[jj] = (bf16_t)tf[jj];
            w9[ks] = v;
        }
        b9v = rv ? bd1[oD] : 0.0f;
    }
    __syncthreads();

    // ---------- Phase 8: y0 = silu(vals @ Wd0^T + bd0)  (N=106 padded to 112; 14 tasks) ----------
    // ---- Prefetch phase-10 weights Wd2 [64][85] first (element-guarded, one phase ahead) ----
    bf16x8 w10[3]; float b10v = 0.0f;
    if (wave < 8) {
        const float* wrow = &Wd2[oD * 85];
#pragma unroll
        for (int ks = 0; ks < 3; ++ks) {
            int kb = ks * 32 + quad * 8;
            bf16x8 v;
#pragma unroll
            for (int jj = 0; jj < 8; ++jj) {
                int k = kb + jj;
                v[jj] = (k < 85) ? (bf16_t)wrow[k] : (bf16_t)0.0f;
            }
            w10[ks] = v;
        }
        b10v = bd2[oD];
    }
    if (wave < 14) {
        int mt = wave & 1;
        f32x4 acc = {0.f, 0.f, 0.f, 0.f};
#pragma unroll
        for (int ks = 0; ks < 4; ++ks) {
            bf16x8 av = *(const bf16x8*)&s_x[(mt * 16 + l16) * LDSPAD + ks * 32 + quad * 8];
            acc = __builtin_amdgcn_mfma_f32_16x16x32_bf16(av, w8[ks], acc, 0, 0, 0);
        }
#pragma unroll
        for (int r = 0; r < 4; ++r) {
            int a = mt * 16 + quad * 4 + r;
            float val = acc[r] + b8v;
            s_q[a * LDSPAD + oD] = (bf16_t)(val / (1.0f + __expf(-val)));   // silu(0)=0 for oD>=106
        }
    }
    __syncthreads();

    // ---------- Phase 9: y1 = silu(y0 @ Wd1^T + bd1)  (N=85 padded to 96, K=128; 12 tasks) ----------
    if (wave < 12) {
        int mt = wave & 1;
        f32x4 acc = {0.f, 0.f, 0.f, 0.f};
#pragma unroll
        for (int ks = 0; ks < 4; ++ks) {
            bf16x8 av = *(const bf16x8*)&s_q[(mt * 16 + l16) * LDSPAD + ks * 32 + quad * 8];
            acc = __builtin_amdgcn_mfma_f32_16x16x32_bf16(av, w9[ks], acc, 0, 0, 0);
        }
#pragma unroll
        for (int r = 0; r < 4; ++r) {
            int a = mt * 16 + quad * 4 + r;
            float val = acc[r] + b9v;
            s_k[a * LDSPAD + oD] = (bf16_t)(val / (1.0f + __expf(-val)));   // zero for oD>=85
        }
    }
    __syncthreads();

    // ---------- Phase 10: y2 = y1 @ Wd2^T + bd2  (N=64, K=96; 8 tasks) ----------
    if (wave < 8) {
        int mt = wave & 1;
        f32x4 acc = {0.f, 0.f, 0.f, 0.f};
#pragma unroll
        for (int ks = 0; ks < 3; ++ks) {
            bf16x8 av = *(const bf16x8*)&s_k[(mt * 16 + l16) * LDSPAD + ks * 32 + quad * 8];
            acc = __builtin_amdgcn_mfma_f32_16x16x32_bf16(av, w10[ks], acc, 0, 0, 0);
        }
#pragma unroll
        for (int r = 0; r < 4; ++r) {
            int a = mt * 16 + quad * 4 + r;
            s_y2[a * 66 + oD] = acc[r] + b10v;
        }
    }
    __syncthreads();

    // ---------- Phase 11: log_softmax over 64 cols, write f32 out (vectorized) ----------
    if (tid < 256) {
        int r = tid >> 3, sub = tid & 7;                   // 8 threads/row, 8 cols each
        float v[8]; float mx = -1e30f;
#pragma unroll
        for (int c = 0; c < 8; ++c) { v[c] = s_y2[r * 66 + sub * 8 + c]; mx = fmaxf(mx, v[c]); }
#pragma unroll
        for (int s = 1; s < 8; s <<= 1) mx = fmaxf(mx, __shfl_xor(mx, s, 64));
        float sum = 0.0f;
#pragma unroll
        for (int c = 0; c < 8; ++c) sum += __expf(v[c] - mx);
#pragma unroll
        for (int s = 1; s < 8; s <<= 1) sum += __shfl_xor(sum, s, 64);
        float lse = mx + __logf(sum);
        float4 o0 = make_float4(v[0] - lse, v[1] - lse, v[2] - lse, v[3] - lse);
        float4 o1 = make_float4(v[4] - lse, v[5] - lse, v[6] - lse, v[7] - lse);
        float* op = &out[(base + r) * 64 + sub * 8];
        *(float4*)op = o0;
        *(float4*)(op + 4) = o1;
    }
}

extern "C" void kernel_launch(void* const* d_in, const int* in_sizes, int n_in,
                              void* d_out, int out_size, void* d_ws, size_t ws_size,
                              hipStream_t stream) {
    const float* h     = (const float*)d_in[0];
    const float* pos   = (const float*)d_in[1];
    const float* ntype = (const float*)d_in[2];
    // d_in[3] = batch (int32): structure is arange//32 (sorted, 32/graph) — used implicitly
    const float* Wemb  = (const float*)d_in[4];
    const float* Wqkv  = (const float*)d_in[5];
    const float* bqkv  = (const float*)d_in[6];
    // d_in[7] = W_b, d_in[8] = b_b: per-row bias cancels in softmax -> unused
    const float* Wg    = (const float*)d_in[9];
    const float* bg    = (const float*)d_in[10];
    const float* Wt    = (const float*)d_in[11];
    const float* bt    = (const float*)d_in[12];
    const float* Wd0   = (const float*)d_in[13];
    const float* bd0   = (const float*)d_in[14];
    const float* Wd1   = (const float*)d_in[15];
    const float* bd1   = (const float*)d_in[16];
    const float* Wd2   = (const float*)d_in[17];
    const float* bd2   = (const float*)d_in[18];
    float* out = (float*)d_out;

    nextdist_fused<<<dim3(64), dim3(1024), 0, stream>>>(
        h, pos, ntype, Wemb, Wqkv, bqkv, Wg, bg, Wt, bt,
        Wd0, bd0, Wd1, bd1, Wd2, bd2, out);
}

// Round 6
// 103.218 us; speedup vs baseline: 1.2091x; 1.2091x over previous
//
#include <hip/hip_runtime.h>

typedef __bf16 bf16_t;
typedef __bf16 bf16x8 __attribute__((ext_vector_type(8)));
typedef float  f32x4  __attribute__((ext_vector_type(4)));

#define HPAD   132          // f32 h-tile row stride (528B, 16B multiple)
#define LDSPAD 136          // bf16 tile stride: 272B (16B multiple)
#define VPAD   40           // 32 + 8 pad -> 80B stride

// d_ws layout (bf16 elements)
#define WQ_OFF   0          // Wqkv  [384][128]
#define WD0_OFF  49152      // Wd0   [112][128]  rows >=106 zero
#define WD1_OFF  63488      // Wd1   [96][128]   rows >=85 / cols >=106 zero
#define WD2_OFF  75776      // Wd2   [64][96]    cols >=85 zero
#define WS_ELEMS 81920      // 163840 bytes total

__global__ __launch_bounds__(256)
void preconvert(const float* __restrict__ Wqkv, const float* __restrict__ Wd0,
                const float* __restrict__ Wd1, const float* __restrict__ Wd2,
                bf16_t* __restrict__ ws) {
    int i = blockIdx.x * 256 + threadIdx.x;
    if (i >= WS_ELEMS) return;
    if (i < WD0_OFF) {
        ws[i] = (bf16_t)Wqkv[i];
    } else if (i < WD1_OFF) {
        int j = i - WD0_OFF, r = j >> 7, c = j & 127;
        ws[i] = (r < 106) ? (bf16_t)Wd0[r * 128 + c] : (bf16_t)0.0f;
    } else if (i < WD2_OFF) {
        int j = i - WD1_OFF, r = j >> 7, c = j & 127;
        ws[i] = (r < 85 && c < 106) ? (bf16_t)Wd1[r * 106 + c] : (bf16_t)0.0f;
    } else {
        int j = i - WD2_OFF, r = j / 96, c = j - r * 96;
        ws[i] = (c < 85) ? (bf16_t)Wd2[r * 85 + c] : (bf16_t)0.0f;
    }
}

// __launch_bounds__(1024, 4): 4 waves/EU min = 1 block/CU -> VGPR budget 128.
// Round-5 evidence: default heuristic targeted 2 blocks/CU (VGPR cap 64) and
// spilled the ~100 VGPRs of prefetched weight fragments (WRITE_SIZE 512KB->6.4MB).
__global__ __launch_bounds__(1024, 4)
void nextdist_fused(const float* __restrict__ h,      // [2048][128]
                    const float* __restrict__ pos,    // [2048][3]
                    const float* __restrict__ ntype,  // [64][64]
                    const float* __restrict__ Wemb,   // [128][64]
                    const float* __restrict__ bqkv,   // [384]
                    const float* __restrict__ Wg,     // [128]
                    const float* __restrict__ bg,     // [1]
                    const float* __restrict__ Wt,     // [32]
                    const float* __restrict__ bt,     // [1]
                    const float* __restrict__ bd0,    // [106]
                    const float* __restrict__ bd1,    // [85]
                    const float* __restrict__ bd2,    // [64]
                    const bf16_t* __restrict__ ws,    // packed bf16 weights
                    float* __restrict__ out)          // [2048][64]
{
    __shared__ __align__(16) float  s_hf[32 * HPAD];     // h tile, f32 (residual + x source)
    __shared__ __align__(16) bf16_t s_x [32 * LDSPAD];   // x (bf16), later vals
    __shared__ __align__(16) bf16_t s_q [32 * LDSPAD];   // q, later y0 (zero-padded cols 106..127)
    __shared__ __align__(16) bf16_t s_k [32 * LDSPAD];   // k, later y1 (zero-padded cols 85..95)
    __shared__ __align__(16) bf16_t s_vT[128 * VPAD];    // v transposed: [feat][atom]
    __shared__ __align__(16) bf16_t s_p [32 * VPAD];     // softmax probs (bf16)
    __shared__ __align__(16) float  s_t [32 * 33];       // t matrix, then logits
    __shared__ __align__(16) float  s_y2[32 * 66];       // final pre-softmax logits (f32)
    __shared__ float s_emb[128];
    __shared__ float s_nt[64];
    __shared__ float s_pos[96];
    __shared__ float s_wt[32];
    __shared__ float s_wg[128];
    __shared__ float s_gate[32];

    const bf16_t* __restrict__ Wqkvb = ws + WQ_OFF;
    const bf16_t* __restrict__ Wd0b  = ws + WD0_OFF;
    const bf16_t* __restrict__ Wd1b  = ws + WD1_OFF;
    const bf16_t* __restrict__ Wd2b  = ws + WD2_OFF;

    const int tid  = threadIdx.x;
    const int wave = tid >> 6;           // 0..15
    const int lane = tid & 63;
    const int quad = lane >> 4;
    const int l16  = lane & 15;
    const int g    = blockIdx.x;
    const int base = g * 32;

    // ---------- Phase 1: stage inputs (1024 threads, 1 float4 each) ----------
    {
        int a = tid >> 5, ch = tid & 31;
        *(float4*)&s_hf[a * HPAD + ch * 4] = *(const float4*)&h[(base + a) * 128 + ch * 4];
    }
    if (tid < 96)  s_pos[tid] = pos[base * 3 + tid];
    if (tid < 64)  s_nt[tid]  = ntype[g * 64 + tid];
    if (tid < 32)  s_wt[tid]  = Wt[tid];
    if (tid < 128) s_wg[tid]  = Wg[tid];

    // ---- Early prefetch: Wemb fragments (f32) + phase-3 weights (bf16) into VGPRs ----
    float4 we0, we1;
    {
        int o = tid >> 3, p = tid & 7;
        we0 = *(const float4*)&Wemb[o * 64 + p * 8];
        we1 = *(const float4*)&Wemb[o * 64 + p * 8 + 4];
    }
    bf16x8 wq[3][4]; float bq3[3];
#pragma unroll
    for (int t3 = 0; t3 < 3; ++t3) {
        int t = wave + t3 * 16;
        int o = (t >> 1) * 16 + l16;                      // 0..383, each exactly once
        const bf16_t* wrow = &Wqkvb[o * 128];
#pragma unroll
        for (int ks = 0; ks < 4; ++ks)
            wq[t3][ks] = *(const bf16x8*)&wrow[ks * 32 + quad * 8];
        bq3[t3] = bqkv[o];
    }
    __syncthreads();

    // ---------- Phase 1b: emb = W_emb @ next_type[g]  (8 threads / output) ----------
    {
        int o = tid >> 3, p = tid & 7;
        const float* nt8 = &s_nt[p * 8];
        float acc = we0.x * nt8[0] + we0.y * nt8[1] + we0.z * nt8[2] + we0.w * nt8[3]
                  + we1.x * nt8[4] + we1.y * nt8[5] + we1.z * nt8[6] + we1.w * nt8[7];
#pragma unroll
        for (int s = 1; s < 8; s <<= 1) acc += __shfl_xor(acc, s, 64);
        if (p == 0) s_emb[o] = acc;
    }
    __syncthreads();

    // ---------- Phase 2: x = h * emb (bf16 for MFMA); gate = sigmoid(x.Wg + bg) ----------
    for (int c = tid; c < 4096; c += 1024) {
        int a = c >> 7, f = c & 127;
        s_x[a * LDSPAD + f] = (bf16_t)(s_hf[a * HPAD + f] * s_emb[f]);
    }
    if (tid < 256) {
        int r = tid >> 3, p = tid & 7;
        float acc = 0.0f;
#pragma unroll
        for (int f = p * 16; f < p * 16 + 16; ++f) acc += s_hf[r * HPAD + f] * s_emb[f] * s_wg[f];
#pragma unroll
        for (int s = 1; s < 8; s <<= 1) acc += __shfl_xor(acc, s, 64);
        if (p == 0) s_gate[r] = 1.0f / (1.0f + __expf(-(acc + bg[0])));
    }
    __syncthreads();

    // ---------- Phase 3: qkv = x @ Wqkv^T + bqkv  (48 tile-tasks; weights prefetched) ----------
    {
        // mt = (wave + 16*t3) & 1 = wave & 1  -> A-fragments shared across the 3 tasks
        int mt = wave & 1;
        bf16x8 av[4];
#pragma unroll
        for (int ks = 0; ks < 4; ++ks)
            av[ks] = *(const bf16x8*)&s_x[(mt * 16 + l16) * LDSPAD + ks * 32 + quad * 8];
#pragma unroll
        for (int t3 = 0; t3 < 3; ++t3) {
            int t = wave + t3 * 16;
            int o = (t >> 1) * 16 + l16;
            f32x4 acc = {0.f, 0.f, 0.f, 0.f};
#pragma unroll
            for (int ks = 0; ks < 4; ++ks)
                acc = __builtin_amdgcn_mfma_f32_16x16x32_bf16(av[ks], wq[t3][ks], acc, 0, 0, 0);
            float bias = bq3[t3];
#pragma unroll
            for (int r = 0; r < 4; ++r) {
                int a = mt * 16 + quad * 4 + r;
                float val = acc[r] + bias;
                if (o < 128)      s_q[a * LDSPAD + o]         = (bf16_t)val;
                else if (o < 256) s_k[a * LDSPAD + (o - 128)] = (bf16_t)val;
                else              s_vT[(o - 256) * VPAD + a]  = (bf16_t)val;
            }
        }
    }

    // ---- Prefetch phase-8 weights (held in VGPRs across phases 4-7) ----
    bf16x8 w8[4]; float b8v = 0.0f;
    const int oD = (wave >> 1) * 16 + l16;                 // row index used by phases 8/9/10
    if (wave < 14) {
        const bf16_t* wrow = &Wd0b[oD * 128];
#pragma unroll
        for (int ks = 0; ks < 4; ++ks)
            w8[ks] = *(const bf16x8*)&wrow[ks * 32 + quad * 8];
        b8v = (oD < 106) ? bd0[oD] : 0.0f;
    }

    // ---------- Phase 4: t[i][j] = sum_k Wt[k]*exp(-10*(d_ij - c_k)^2) + bt  (1 elem/thread) ----------
    {
        const float bt0 = bt[0];
        int i = tid >> 5, j = tid & 31;
        float dx = s_pos[i * 3 + 0] - s_pos[j * 3 + 0];
        float dy = s_pos[i * 3 + 1] - s_pos[j * 3 + 1];
        float dz = s_pos[i * 3 + 2] - s_pos[j * 3 + 2];
        float d  = sqrtf(fmaxf(dx * dx + dy * dy + dz * dz, 1e-12f));
        float acc = bt0;
#pragma unroll
        for (int kk = 0; kk < 32; ++kk) {
            float u = d - (float)kk * (10.0f / 31.0f);
            acc += s_wt[kk] * __expf(-10.0f * u * u);
        }
        s_t[i * 33 + j] = acc;
    }
    __syncthreads();

    // ---------- Phase 5: logits = (q@k^T)/sqrt(32) + t   (b_bias cancels in softmax) ----------
    if (wave < 4) {
        int mt = wave >> 1, nt = wave & 1;
        f32x4 acc = {0.f, 0.f, 0.f, 0.f};
#pragma unroll
        for (int ks = 0; ks < 4; ++ks) {
            bf16x8 av = *(const bf16x8*)&s_q[(mt * 16 + l16) * LDSPAD + ks * 32 + quad * 8];
            bf16x8 bv = *(const bf16x8*)&s_k[(nt * 16 + l16) * LDSPAD + ks * 32 + quad * 8];
            acc = __builtin_amdgcn_mfma_f32_16x16x32_bf16(av, bv, acc, 0, 0, 0);
        }
#pragma unroll
        for (int r = 0; r < 4; ++r) {
            int i = mt * 16 + quad * 4 + r, j = nt * 16 + l16;
            s_t[i * 33 + j] = acc[r] * 0.17677669529663687f + s_t[i * 33 + j];
        }
    }
    __syncthreads();

    // ---------- Phase 6: row softmax -> P (bf16) ----------
    if (tid < 256) {
        int r = tid >> 3, sub = tid & 7;                  // 8 threads/row, 4 cols each
        float v[4]; float mx = -1e30f;
#pragma unroll
        for (int c = 0; c < 4; ++c) { v[c] = s_t[r * 33 + sub * 4 + c]; mx = fmaxf(mx, v[c]); }
#pragma unroll
        for (int s = 1; s < 8; s <<= 1) mx = fmaxf(mx, __shfl_xor(mx, s, 64));
        float sum = 0.0f;
#pragma unroll
        for (int c = 0; c < 4; ++c) { v[c] = __expf(v[c] - mx); sum += v[c]; }
#pragma unroll
        for (int s = 1; s < 8; s <<= 1) sum += __shfl_xor(sum, s, 64);
        float inv = 1.0f / sum;
#pragma unroll
        for (int c = 0; c < 4; ++c) s_p[r * VPAD + sub * 4 + c] = (bf16_t)(v[c] * inv);
    }
    __syncthreads();

    // ---------- Phase 7: vals = (P @ V) * gate + x  (16 tile-tasks, 1/wave) ----------
    {
        int nt = wave >> 1, mt = wave & 1;                 // nt 0..7 feature tile
        bf16x8 av = *(const bf16x8*)&s_p[(mt * 16 + l16) * VPAD + quad * 8];
        bf16x8 bv = *(const bf16x8*)&s_vT[(nt * 16 + l16) * VPAD + quad * 8];
        f32x4 acc = {0.f, 0.f, 0.f, 0.f};
        acc = __builtin_amdgcn_mfma_f32_16x16x32_bf16(av, bv, acc, 0, 0, 0);
#pragma unroll
        for (int r = 0; r < 4; ++r) {
            int a = mt * 16 + quad * 4 + r, f = nt * 16 + l16;
            float val = acc[r] * s_gate[a] + s_hf[a * HPAD + f] * s_emb[f];
            s_x[a * LDSPAD + f] = (bf16_t)val;             // vals overwrite x
        }
    }
    if (tid < 512) {                                       // zero y0 cols 112..127 (K-pad for phase 9)
        int a = tid >> 4, c = 112 + (tid & 15);
        s_q[a * LDSPAD + c] = (bf16_t)0.0f;
    }

    // ---- Prefetch phase-9 weights (one phase ahead) ----
    bf16x8 w9[4]; float b9v = 0.0f;
    if (wave < 12) {
        const bf16_t* wrow = &Wd1b[oD * 128];
#pragma unroll
        for (int ks = 0; ks < 4; ++ks)
            w9[ks] = *(const bf16x8*)&wrow[ks * 32 + quad * 8];
        b9v = (oD < 85) ? bd1[oD] : 0.0f;
    }
    __syncthreads();

    // ---------- Phase 8: y0 = silu(vals @ Wd0^T + bd0)  (N=106 padded to 112; 14 tasks) ----------
    // ---- Prefetch phase-10 weights first (one phase ahead) ----
    bf16x8 w10[3]; float b10v = 0.0f;
    if (wave < 8) {
        const bf16_t* wrow = &Wd2b[oD * 96];
#pragma unroll
        for (int ks = 0; ks < 3; ++ks)
            w10[ks] = *(const bf16x8*)&wrow[ks * 32 + quad * 8];
        b10v = bd2[oD];
    }
    if (wave < 14) {
        int mt = wave & 1;
        f32x4 acc = {0.f, 0.f, 0.f, 0.f};
#pragma unroll
        for (int ks = 0; ks < 4; ++ks) {
            bf16x8 av = *(const bf16x8*)&s_x[(mt * 16 + l16) * LDSPAD + ks * 32 + quad * 8];
            acc = __builtin_amdgcn_mfma_f32_16x16x32_bf16(av, w8[ks], acc, 0, 0, 0);
        }
#pragma unroll
        for (int r = 0; r < 4; ++r) {
            int a = mt * 16 + quad * 4 + r;
            float val = acc[r] + b8v;
            s_q[a * LDSPAD + oD] = (bf16_t)(val / (1.0f + __expf(-val)));   // silu(0)=0 for oD>=106
        }
    }
    __syncthreads();

    // ---------- Phase 9: y1 = silu(y0 @ Wd1^T + bd1)  (N=85 padded to 96, K=128; 12 tasks) ----------
    if (wave < 12) {
        int mt = wave & 1;
        f32x4 acc = {0.f, 0.f, 0.f, 0.f};
#pragma unroll
        for (int ks = 0; ks < 4; ++ks) {
            bf16x8 av = *(const bf16x8*)&s_q[(mt * 16 + l16) * LDSPAD + ks * 32 + quad * 8];
            acc = __builtin_amdgcn_mfma_f32_16x16x32_bf16(av, w9[ks], acc, 0, 0, 0);
        }
#pragma unroll
        for (int r = 0; r < 4; ++r) {
            int a = mt * 16 + quad * 4 + r;
            float val = acc[r] + b9v;
            s_k[a * LDSPAD + oD] = (bf16_t)(val / (1.0f + __expf(-val)));   // zero for oD>=85
        }
    }
    __syncthreads();

    // ---------- Phase 10: y2 = y1 @ Wd2^T + bd2  (N=64, K=96; 8 tasks) ----------
    if (wave < 8) {
        int mt = wave & 1;
        f32x4 acc = {0.f, 0.f, 0.f, 0.f};
#pragma unroll
        for (int ks = 0; ks < 3; ++ks) {
            bf16x8 av = *(const bf16x8*)&s_k[(mt * 16 + l16) * LDSPAD + ks * 32 + quad * 8];
            acc = __builtin_amdgcn_mfma_f32_16x16x32_bf16(av, w10[ks], acc, 0, 0, 0);
        }
#pragma unroll
        for (int r = 0; r < 4; ++r) {
            int a = mt * 16 + quad * 4 + r;
            s_y2[a * 66 + oD] = acc[r] + b10v;
        }
    }
    __syncthreads();

    // ---------- Phase 11: log_softmax over 64 cols, write f32 out (vectorized) ----------
    if (tid < 256) {
        int r = tid >> 3, sub = tid & 7;                   // 8 threads/row, 8 cols each
        float v[8]; float mx = -1e30f;
#pragma unroll
        for (int c = 0; c < 8; ++c) { v[c] = s_y2[r * 66 + sub * 8 + c]; mx = fmaxf(mx, v[c]); }
#pragma unroll
        for (int s = 1; s < 8; s <<= 1) mx = fmaxf(mx, __shfl_xor(mx, s, 64));
        float sum = 0.0f;
#pragma unroll
        for (int c = 0; c < 8; ++c) sum += __expf(v[c] - mx);
#pragma unroll
        for (int s = 1; s < 8; s <<= 1) sum += __shfl_xor(sum, s, 64);
        float lse = mx + __logf(sum);
        float4 o0 = make_float4(v[0] - lse, v[1] - lse, v[2] - lse, v[3] - lse);
        float4 o1 = make_float4(v[4] - lse, v[5] - lse, v[6] - lse, v[7] - lse);
        float* op = &out[(base + r) * 64 + sub * 8];
        *(float4*)op = o0;
        *(float4*)(op + 4) = o1;
    }
}

extern "C" void kernel_launch(void* const* d_in, const int* in_sizes, int n_in,
                              void* d_out, int out_size, void* d_ws, size_t ws_size,
                              hipStream_t stream) {
    const float* h     = (const float*)d_in[0];
    const float* pos   = (const float*)d_in[1];
    const float* ntype = (const float*)d_in[2];
    // d_in[3] = batch (int32): structure is arange//32 (sorted, 32/graph) — used implicitly
    const float* Wemb  = (const float*)d_in[4];
    const float* Wqkv  = (const float*)d_in[5];
    const float* bqkv  = (const float*)d_in[6];
    // d_in[7] = W_b, d_in[8] = b_b: per-row bias cancels in softmax -> unused
    const float* Wg    = (const float*)d_in[9];
    const float* bg    = (const float*)d_in[10];
    const float* Wt    = (const float*)d_in[11];
    const float* bt    = (const float*)d_in[12];
    const float* Wd0   = (const float*)d_in[13];
    const float* bd0   = (const float*)d_in[14];
    const float* Wd1   = (const float*)d_in[15];
    const float* bd1   = (const float*)d_in[16];
    const float* Wd2   = (const float*)d_in[17];
    const float* bd2   = (const float*)d_in[18];
    float* out = (float*)d_out;
    bf16_t* ws = (bf16_t*)d_ws;

    preconvert<<<dim3((WS_ELEMS + 255) / 256), dim3(256), 0, stream>>>(Wqkv, Wd0, Wd1, Wd2, ws);
    nextdist_fused<<<dim3(64), dim3(1024), 0, stream>>>(
        h, pos, ntype, Wemb, bqkv, Wg, bg, Wt, bt,
        bd0, bd1, bd2, ws, out);
}